// Round 3
// baseline (170.413 us; speedup 1.0000x reference)
//
#include <hip/hip_runtime.h>
#include <hip/hip_bf16.h>

#define NN 512
#define DD 64
#define TOPK 20
#define BB 128

// ---------------- K12: fused [k2 gemm blocks 0..1023] + [k1 topk blocks 1024..1151]
// k1 part: one wave per node; f64 math, identical accumulation order / tie-break
// as round-1 verified kernel -> bit-identical topk.
// k2 part: z = data @ fc_w^T + fc_b, plus z-only attention partial scores
// (es_src/es_dst are folded in later, inside k3 phase 1).
__global__ __launch_bounds__(256) void k12_fused(const float* __restrict__ data,
                                                 const float* __restrict__ fc_w,
                                                 const float* __restrict__ fc_b,
                                                 const float* __restrict__ emb,
                                                 const float* __restrict__ attn_w,
                                                 float* __restrict__ z,
                                                 float* __restrict__ zsrc,
                                                 float* __restrict__ zdst,
                                                 int* __restrict__ topk,
                                                 float* __restrict__ es_src,
                                                 float* __restrict__ es_dst) {
    __shared__ float As [64][68];
    __shared__ float WsT[64][68];   // WsT[f][d] = fc_w[d][f]
    __shared__ float redA[64][17];
    __shared__ float redB[64][17];
    const int t = threadIdx.x;

    if (blockIdx.x < 1024) {
        // ================= k2: GEMM =================
        const long r0 = (long)blockIdx.x * 64;
        const float4* data4 = (const float4*)data;
        const float4* fcw4  = (const float4*)fc_w;

        for (int m = t; m < 1024; m += 256) {
            const int r = m >> 4, c4 = m & 15;
            *(float4*)&As[r][c4 * 4] = data4[(r0 + r) * 16 + c4];
        }
        for (int m = t; m < 1024; m += 256) {
            const int d = m >> 4, f4 = m & 15;
            float4 v = fcw4[d * 16 + f4];
            WsT[f4 * 4 + 0][d] = v.x;
            WsT[f4 * 4 + 1][d] = v.y;
            WsT[f4 * 4 + 2][d] = v.z;
            WsT[f4 * 4 + 3][d] = v.w;
        }
        __syncthreads();

        const int tr = t >> 4, tc = t & 15;
        float acc[4][4] = {};
        for (int k0 = 0; k0 < 64; k0 += 4) {
            float4 a4[4], b4[4];
            #pragma unroll
            for (int i = 0; i < 4; ++i) a4[i] = *(float4*)&As[tr * 4 + i][k0];
            #pragma unroll
            for (int kk = 0; kk < 4; ++kk) b4[kk] = *(float4*)&WsT[k0 + kk][tc * 4];
            #pragma unroll
            for (int i = 0; i < 4; ++i) {
                acc[i][0] += a4[i].x * b4[0].x + a4[i].y * b4[1].x + a4[i].z * b4[2].x + a4[i].w * b4[3].x;
                acc[i][1] += a4[i].x * b4[0].y + a4[i].y * b4[1].y + a4[i].z * b4[2].y + a4[i].w * b4[3].y;
                acc[i][2] += a4[i].x * b4[0].z + a4[i].y * b4[1].z + a4[i].z * b4[2].z + a4[i].w * b4[3].z;
                acc[i][3] += a4[i].x * b4[0].w + a4[i].y * b4[1].w + a4[i].z * b4[2].w + a4[i].w * b4[3].w;
            }
        }
        float bias[4], aw0[4], aw2[4];
        #pragma unroll
        for (int j = 0; j < 4; ++j) {
            bias[j] = fc_b[tc * 4 + j];
            aw0[j]  = attn_w[tc * 4 + j];
            aw2[j]  = attn_w[128 + tc * 4 + j];
        }
        #pragma unroll
        for (int i = 0; i < 4; ++i) {
            float zb[4];
            #pragma unroll
            for (int j = 0; j < 4; ++j) zb[j] = acc[i][j] + bias[j];
            float4 vv; vv.x = zb[0]; vv.y = zb[1]; vv.z = zb[2]; vv.w = zb[3];
            *(float4*)&z[(r0 + tr * 4 + i) * 64 + tc * 4] = vv;
            redA[tr * 4 + i][tc] = zb[0] * aw0[0] + zb[1] * aw0[1] + zb[2] * aw0[2] + zb[3] * aw0[3];
            redB[tr * 4 + i][tc] = zb[0] * aw2[0] + zb[1] * aw2[1] + zb[2] * aw2[2] + zb[3] * aw2[3];
        }
        __syncthreads();
        if (t < 64) {
            float sA = 0.f, sB = 0.f;
            #pragma unroll
            for (int k = 0; k < 16; ++k) { sA += redA[t][k]; sB += redB[t][k]; }
            zsrc[r0 + t] = sA;
            zdst[r0 + t] = sB;
        }
    } else {
        // ================= k1: topk + emb-attn partials =================
        const int i = (blockIdx.x - 1024) * 4 + (t >> 6);
        const int lane = t & 63;
        const float4* e4 = (const float4*)emb;

        double dot[8] = {0,0,0,0,0,0,0,0};
        double dj [8] = {0,0,0,0,0,0,0,0};
        double di = 0.0;

        for (int c = 0; c < 16; ++c) {
            float4 wi4 = e4[i * 16 + c];
            double wx = wi4.x, wy = wi4.y, wz = wi4.z, ww = wi4.w;
            di += wx * wx; di += wy * wy; di += wz * wz; di += ww * ww;
            #pragma unroll
            for (int r = 0; r < 8; ++r) {
                float4 v = e4[(lane * 8 + r) * 16 + c];
                double vx = v.x, vy = v.y, vz = v.z, vw = v.w;
                dot[r] += wx * vx; dot[r] += wy * vy; dot[r] += wz * vz; dot[r] += ww * vw;
                dj [r] += vx * vx; dj [r] += vy * vy; dj [r] += vz * vz; dj [r] += vw * vw;
            }
        }
        const double nrm_i = sqrt(di);
        double v[8];
        #pragma unroll
        for (int r = 0; r < 8; ++r) v[r] = dot[r] / (nrm_i * sqrt(dj[r]));

        for (int k = 0; k < TOPK; ++k) {
            double bv = v[0]; int br = 0;
            #pragma unroll
            for (int r = 1; r < 8; ++r) if (v[r] > bv) { bv = v[r]; br = r; }
            int bi = lane * 8 + br;
            #pragma unroll
            for (int off = 32; off > 0; off >>= 1) {
                double ov = __shfl_xor(bv, off);
                int    oi = __shfl_xor(bi, off);
                if (ov > bv || (ov == bv && oi < bi)) { bv = ov; bi = oi; }
            }
            if (lane == 0) topk[i * TOPK + k] = bi;
            if ((bi >> 3) == lane) v[bi & 7] = -1e300;
        }

        float wf = emb[i * 64 + lane];
        float v1 = wf * attn_w[64 + lane];
        float v2 = wf * attn_w[192 + lane];
        #pragma unroll
        for (int off = 32; off > 0; off >>= 1) {
            v1 += __shfl_xor(v1, off);
            v2 += __shfl_xor(v2, off);
        }
        if (lane == 0) { es_src[i] = v1; es_dst[i] = v2; }
    }
}

// ---------------- K3: LDS-staged gather + one-shot softmax + BN partials --------
// grid: 512 blocks = (batch b, feature-quarter dq). Phase 2 uses float4 LDS
// gathers (lane owns 4 cols) -> 4x fewer LDS instructions than b32.
__global__ __launch_bounds__(256) void k3_attn(const float* __restrict__ z,
                                               const float* __restrict__ zsrc,
                                               const float* __restrict__ zdst,
                                               const float* __restrict__ es_src,
                                               const float* __restrict__ es_dst,
                                               const int* __restrict__ topk,
                                               const float* __restrict__ emb,
                                               const float* __restrict__ attn_b_p,
                                               float* __restrict__ rst,
                                               double* __restrict__ bsum,
                                               double* __restrict__ bsum2) {
    __shared__ float  zs[512 * 16];          // 32 KB
    __shared__ double alf_pool[2560];        // 20 KB: alpha[256][20] / BN-reduce alias
    __shared__ unsigned short sIdx[256 * 20];// 10 KB
    float* alf = (float*)alf_pool;

    const int b    = blockIdx.x >> 2;
    const int dq   = blockIdx.x & 3;
    const int doff = dq * 16;
    const int t    = threadIdx.x;
    const float attn_b = *attn_b_p;
    const long b512 = (long)b * NN;

    float4* zs4 = (float4*)zs;
    for (int m = t; m < 2048; m += 256) {
        const int n = m >> 2, c4 = m & 3;
        zs4[m] = *(const float4*)(z + (b512 + n) * 64 + doff + c4 * 4);
    }
    __syncthreads();

    const int c4 = t & 3;
    const int rq = t >> 2;                   // 0..63
    double s1[4] = {0,0,0,0}, s2[4] = {0,0,0,0};

    for (int chunk = 0; chunk < 2; ++chunk) {
        // ---- phase 1: one thread per row computes the 20-edge softmax ----
        {
            const int n = chunk * 256 + t;
            const float sd = zdst[b512 + n] + es_dst[n] + attn_b;
            float ev[TOPK];
            float m0 = -1e30f;
            #pragma unroll
            for (int tt = 0; tt < TOPK; ++tt) {
                const int s = topk[n + tt * NN];   // scrambled flat edge list
                sIdx[t * TOPK + tt] = (unsigned short)s;
                float e = zsrc[b512 + s] + es_src[s] + sd;
                e = (e >= 0.f) ? e : 0.2f * e;
                ev[tt] = e;
                m0 = fmaxf(m0, e);
            }
            float dsum = 0.f;
            #pragma unroll
            for (int tt = 0; tt < TOPK; ++tt) { ev[tt] = __expf(ev[tt] - m0); dsum += ev[tt]; }
            const float inv = 1.0f / dsum;
            #pragma unroll
            for (int tt = 0; tt < TOPK; ++tt) alf[t * TOPK + tt] = ev[tt] * inv;
        }
        __syncthreads();

        // ---- phase 2: float4 gather-FMA from LDS; 4 lanes x 4 rows per thread --
        #pragma unroll
        for (int it = 0; it < 4; ++it) {
            const int nl = it * 64 + rq;
            const int n  = chunk * 256 + nl;
            float4 acc = {0.f, 0.f, 0.f, 0.f};
            #pragma unroll
            for (int tt = 0; tt < TOPK; ++tt) {
                const float a = alf[nl * TOPK + tt];
                const float4 zv = zs4[(int)sIdx[nl * TOPK + tt] * 4 + c4];
                acc.x += a * zv.x; acc.y += a * zv.y; acc.z += a * zv.z; acc.w += a * zv.w;
            }
            const float4 ev = *(const float4*)&emb[n * 64 + doff + c4 * 4];
            float4 r;
            r.x = acc.x * ev.x; r.y = acc.y * ev.y; r.z = acc.z * ev.z; r.w = acc.w * ev.w;
            *(float4*)&rst[(b512 + n) * 64 + doff + c4 * 4] = r;
            s1[0] += (double)r.x; s2[0] += (double)r.x * (double)r.x;
            s1[1] += (double)r.y; s2[1] += (double)r.y * (double)r.y;
            s1[2] += (double)r.z; s2[2] += (double)r.z * (double)r.z;
            s1[3] += (double)r.w; s2[3] += (double)r.w * (double)r.w;
        }
        __syncthreads();   // before next chunk overwrites alf/sIdx
    }

    // ---- BN partials: alias reduce arrays onto alf_pool ----
    double* r1 = alf_pool;
    double* r2 = alf_pool + 1024;
    #pragma unroll
    for (int j = 0; j < 4; ++j) {
        r1[(c4 * 4 + j) * 64 + rq] = s1[j];
        r2[(c4 * 4 + j) * 64 + rq] = s2[j];
    }
    __syncthreads();
    if (t < 16) {
        double a = 0.0, bb = 0.0;
        for (int q = 0; q < 64; ++q) { a += r1[t * 64 + q]; bb += r2[t * 64 + q]; }
        bsum [blockIdx.x * 16 + t] = a;
        bsum2[blockIdx.x * 16 + t] = bb;
    }
}

// ---------------- K4: BN finalize -> scale/bias ---------------------------------
__global__ __launch_bounds__(512) void k4_bn(const double* __restrict__ bsum,
                                             const double* __restrict__ bsum2,
                                             const float* __restrict__ gamma,
                                             const float* __restrict__ beta,
                                             float* __restrict__ scaleArr,
                                             float* __restrict__ biasArr) {
    __shared__ double r1[512], r2[512];
    const int t = threadIdx.x;
    const int d = t & 63, part = t >> 6;     // 8 parts
    const int dq = d >> 4, c = d & 15;
    double s = 0.0, s2 = 0.0;
    for (int b = part; b < BB; b += 8) {
        const int blk = b * 4 + dq;
        s  += bsum [blk * 16 + c];
        s2 += bsum2[blk * 16 + c];
    }
    r1[part * 64 + d] = s; r2[part * 64 + d] = s2;
    __syncthreads();
    if (t < 64) {
        double S = 0.0, S2 = 0.0;
        #pragma unroll
        for (int p = 0; p < 8; ++p) { S += r1[p * 64 + t]; S2 += r2[p * 64 + t]; }
        const double M = (double)BB * (double)NN;
        const double mu  = S / M;
        const double var = S2 / M - mu * mu;
        const float scale = (float)((double)gamma[t] / sqrt(var + 1e-5));
        scaleArr[t] = scale;
        biasArr[t]  = beta[t] - (float)mu * scale;
    }
}

// ---------------- K5: BN apply + ReLU + out_w dot (16 rows/block) ---------------
__global__ __launch_bounds__(256) void k5_out(const float* __restrict__ rst,
                                              const float* __restrict__ scaleArr,
                                              const float* __restrict__ biasArr,
                                              const float* __restrict__ out_w,
                                              const float* __restrict__ out_b_p,
                                              float* __restrict__ out) {
    const int wid = threadIdx.x >> 6, lane = threadIdx.x & 63;
    const float sc = scaleArr[lane], bi = biasArr[lane], ow = out_w[lane];
    const float ob = *out_b_p;
    const long rowbase = (long)blockIdx.x * 16 + wid * 4;
    float v[4];
    #pragma unroll
    for (int rr = 0; rr < 4; ++rr)
        v[rr] = fmaxf(rst[(rowbase + rr) * 64 + lane] * sc + bi, 0.f) * ow;
    #pragma unroll
    for (int off = 32; off > 0; off >>= 1)
        #pragma unroll
        for (int rr = 0; rr < 4; ++rr) v[rr] += __shfl_down(v[rr], off);
    if (lane == 0)
        #pragma unroll
        for (int rr = 0; rr < 4; ++rr) out[rowbase + rr] = v[rr] + ob;
}

extern "C" void kernel_launch(void* const* d_in, const int* in_sizes, int n_in,
                              void* d_out, int out_size, void* d_ws, size_t ws_size,
                              hipStream_t stream) {
    const float* data   = (const float*)d_in[0];
    const float* emb    = (const float*)d_in[1];
    const float* fc_w   = (const float*)d_in[2];
    const float* fc_b   = (const float*)d_in[3];
    const float* attn_w = (const float*)d_in[4];
    const float* attn_b = (const float*)d_in[5];
    const float* gamma  = (const float*)d_in[6];
    const float* beta   = (const float*)d_in[7];
    const float* out_w  = (const float*)d_in[8];
    const float* out_b  = (const float*)d_in[9];
    float* out = (float*)d_out;

    char* ws = (char*)d_ws;
    float*  z      = (float*) (ws + 0);            // 16 MB
    float*  rst    = (float*) (ws + 16777216);     // 16 MB
    float*  zsrc   = (float*) (ws + 33554432);     // 256 KB
    float*  zdst   = (float*) (ws + 33816576);     // 256 KB
    int*    topk   = (int*)   (ws + 34078720);     // 40 KB
    float*  es_src = (float*) (ws + 34119680);     // 2 KB
    float*  es_dst = (float*) (ws + 34121728);     // 2 KB
    double* bsum   = (double*)(ws + 34123776);     // 64 KB
    double* bsum2  = (double*)(ws + 34189312);     // 64 KB
    float*  scaleA = (float*) (ws + 34254848);     // 256 B
    float*  biasA  = (float*) (ws + 34255104);     // 256 B

    k12_fused<<<1152, 256, 0, stream>>>(data, fc_w, fc_b, emb, attn_w,
                                        z, zsrc, zdst, topk, es_src, es_dst);
    k3_attn<<<BB * 4, 256, 0, stream>>>(z, zsrc, zdst, es_src, es_dst, topk, emb,
                                        attn_b, rst, bsum, bsum2);
    k4_bn<<<1, 512, 0, stream>>>(bsum, bsum2, gamma, beta, scaleA, biasA);
    k5_out<<<4096, 256, 0, stream>>>(rst, scaleA, biasA, out_w, out_b, out);
}